// Round 2
// baseline (977.211 us; speedup 1.0000x reference)
//
#include <hip/hip_runtime.h>
#include <stdint.h>

// Problem constants (B, N, H, L) = (4096, 512, 1024, 8)
static constexpr int B_DIM = 4096;
static constexpr int N_DIM = 512;
static constexpr int H_DIM = 1024;
static constexpr int L_DIM = 8;
static constexpr int HL    = H_DIM * L_DIM;   // 8192
static constexpr int KC    = 2 * N_DIM;       // 1024: xcomb/combW row length [lo|hi]

typedef __attribute__((ext_vector_type(8))) short short8;     // 8 bf16 (4 VGPRs)
typedef __attribute__((ext_vector_type(8))) unsigned short u16x8;
typedef __attribute__((ext_vector_type(4))) float f32x4;

// round-to-nearest-even fp32 -> bf16 (bit pattern)
__device__ __forceinline__ uint16_t f2bf(float f) {
  uint32_t u = __float_as_uint(f);
  u += 0x7fffu + ((u >> 16) & 1u);
  return (uint16_t)(u >> 16);
}

__device__ __forceinline__ void stage16(const uint16_t* g, uint16_t* l) {
  __builtin_amdgcn_global_load_lds(
      (const __attribute__((address_space(1))) void*)g,
      (__attribute__((address_space(3))) void*)l, 16, 0, 0);
}

// ---------- fused prep kernel (8 elems/thread, 16B stores) — UNCHANGED ----------
// region 0: betab = bf16(beta)                              (HL*N/8 threads)
// region 1: xcomb[b,0:512]=bf16(x), [512:1024]=bf16(x^2)    (B*N/8)
// region 2: combW[h,0:512]=bf16(W), [512:1024]=bf16(-0.5*sum_l beta^2) (H*N/8)
static constexpr int PREP_T0 = HL * N_DIM / 8;       // 524288
static constexpr int PREP_T1 = B_DIM * N_DIM / 8;    // 262144
static constexpr int PREP_T2 = H_DIM * N_DIM / 8;    // 65536

__global__ void prep_kernel(const float* __restrict__ x, const float* __restrict__ beta,
                            const float* __restrict__ W,
                            uint16_t* __restrict__ xcomb, uint16_t* __restrict__ betab,
                            uint16_t* __restrict__ combW) {
  int t = blockIdx.x * 256 + threadIdx.x;
  if (t < PREP_T0) {                           // beta cast
    const f32x4* src = (const f32x4*)(beta + (size_t)t * 8);
    f32x4 a = src[0], b = src[1];
    u16x8 o;
#pragma unroll
    for (int i = 0; i < 4; ++i) { o[i] = f2bf(a[i]); o[4 + i] = f2bf(b[i]); }
    *(u16x8*)(betab + (size_t)t * 8) = o;
    return;
  }
  t -= PREP_T0;
  if (t < PREP_T1) {                           // x | x^2
    int bb = t >> 6, n8 = (t & 63) * 8;
    const f32x4* src = (const f32x4*)(x + (size_t)bb * N_DIM + n8);
    f32x4 a = src[0], b = src[1];
    u16x8 lo, hi;
#pragma unroll
    for (int i = 0; i < 4; ++i) {
      lo[i] = f2bf(a[i]);        lo[4 + i] = f2bf(b[i]);
      hi[i] = f2bf(a[i] * a[i]); hi[4 + i] = f2bf(b[i] * b[i]);
    }
    *(u16x8*)(xcomb + (size_t)bb * KC + n8)         = lo;
    *(u16x8*)(xcomb + (size_t)bb * KC + N_DIM + n8) = hi;
    return;
  }
  t -= PREP_T1;                                // W | -0.5*sum_l beta^2
  int h = t >> 6, n8 = (t & 63) * 8;
  const f32x4* wsrc = (const f32x4*)(W + (size_t)h * N_DIM + n8);
  f32x4 wa = wsrc[0], wb = wsrc[1];
  u16x8 lo;
#pragma unroll
  for (int i = 0; i < 4; ++i) { lo[i] = f2bf(wa[i]); lo[4 + i] = f2bf(wb[i]); }
  *(u16x8*)(combW + (size_t)h * KC + n8) = lo;
  float s[8] = {};
#pragma unroll
  for (int l = 0; l < L_DIM; ++l) {
    const f32x4* bsrc = (const f32x4*)(beta + ((size_t)h * L_DIM + l) * N_DIM + n8);
    f32x4 a = bsrc[0], b = bsrc[1];
#pragma unroll
    for (int i = 0; i < 4; ++i) { s[i] += a[i] * a[i]; s[4 + i] += b[i] * b[i]; }
  }
  u16x8 hi;
#pragma unroll
  for (int i = 0; i < 8; ++i) hi[i] = f2bf(-0.5f * s[i]);
  *(u16x8*)(combW + (size_t)h * KC + N_DIM + n8) = hi;
}

// ---------- fused GEMM v3: 256x256 tile, 512 threads, BK=32, triple-buffered ----------
// Counted-vmcnt software pipeline (T3/T4): each iteration issues {W-regload(t+2) +
// 6 global_load_lds(t+2)} = 7 wave-uniform vmem ops, computes tile t, then waits
// vmcnt(7): drains tile t+1's 7 ops (incl. its W regload) while tile t+2 stays in
// flight across the raw s_barrier. Never vmcnt(0) in the main loop.
//
// Per buffer (48 KB, u16 offsets):
//   Ax  [0, 8192):      256 rows x 32 k of x      (4 chunks/row, slot = c ^ (m&3))
//   Ax2 [8192, 16384):  256 rows x 32 k of x^2
//   Bs  [16384, 24576): 256 betab rows x 32 k
// 3 buffers = 144 KB LDS, 1 block/CU, 8 waves (wm 0..1 x wn 0..3).
// W operand: per-lane 16B global loads (combW is 2 MB, L2-resident), rotated
// through 3 short8 regs wf0<-wf1<-wf2 (static indexing only).
// Wave (wm,wn): main acc = rows wm*128+[0,128) x hl-cols wn*64+[0,64)  (8x4 frags)
// lin: wn even -> x-half, wn odd -> x^2-half; h-group (wn>>1)*16+[0,16); partials
// merged in LDS epilogue (stride-36 f32 red tile), then FM butterfly adds.
static constexpr int S_BUF  = 24576;   // u16 per buffer (48 KB)
static constexpr int OFF_A2 = 8192;
static constexpr int OFF_B  = 16384;

template<bool ODD>
__device__ __forceinline__ void compute_tile(
    const uint16_t* __restrict__ L,
    const int (&offA)[8], const int (&offB)[4], short8 wf,
    f32x4 (&acc)[8][4], f32x4 (&lacc)[8])
{
  short8 bf[4];
#pragma unroll
  for (int j = 0; j < 4; ++j) bf[j] = *(const short8*)(L + offB[j]);
  __builtin_amdgcn_s_setprio(1);
#pragma unroll 4
  for (int i = 0; i < 8; ++i) {
    short8 a = *(const short8*)(L + offA[i]);
    short8 a2;
    if constexpr (ODD) a2 = *(const short8*)(L + OFF_A2 + offA[i]);
    else               a2 = a;
#pragma unroll
    for (int j = 0; j < 4; ++j)
      acc[i][j] = __builtin_amdgcn_mfma_f32_16x16x32_bf16(a, bf[j], acc[i][j], 0, 0, 0);
    lacc[i] = __builtin_amdgcn_mfma_f32_16x16x32_bf16(a2, wf, lacc[i], 0, 0, 0);
  }
  __builtin_amdgcn_s_setprio(0);
}

__global__ __launch_bounds__(512) void fm_kernel(
    const uint16_t* __restrict__ xcomb,   // (B, KC)
    const uint16_t* __restrict__ betab,   // (HL, N)
    const uint16_t* __restrict__ combW,   // (H, KC)
    const float* __restrict__ bias,       // (H,)
    float* __restrict__ out)              // (B, H)
{
  __shared__ __align__(16) uint16_t lds[3 * S_BUF];   // 144 KB

  const int tid  = threadIdx.x;
  const int lane = tid & 63;
  const int wave = tid >> 6;            // 0..7
  const int wm = wave >> 2, wn = wave & 3;
  const int fr = lane & 15, quad = lane >> 4;

  // bijective XCD-chunked swizzle: 512 blocks, XCD x gets cids [64x, 64x+64)
  // = 4 bx (B-panels L2-resident) x all 16 by (A streams, LLC-deduped).
  const int bid = blockIdx.x;
  const int cid = (bid & 7) * 64 + (bid >> 3);
  const int bx = cid >> 4, by = cid & 15;
  const int row0 = by * 256, col0 = bx * 256, hcol0 = bx * 32;

  // ---- per-thread staging sources (pre-swizzled global) + LDS dest offsets ----
  const int sA0 = tid, sA1 = tid + 512;
  const int mA0 = sA0 >> 2, cA0 = (sA0 & 3) ^ (mA0 & 3);
  const int mA1 = sA1 >> 2, cA1 = (sA1 & 3) ^ (mA1 & 3);
  const uint16_t* baseA0 = xcomb + (size_t)(row0 + mA0) * KC + cA0 * 8;
  const uint16_t* baseA1 = xcomb + (size_t)(row0 + mA1) * KC + cA1 * 8;
  const uint16_t* baseB0 = betab + (size_t)(col0 + mA0) * N_DIM + cA0 * 8;
  const uint16_t* baseB1 = betab + (size_t)(col0 + mA1) * N_DIM + cA1 * 8;
  const int dA0 = sA0 * 8, dA1 = sA1 * 8;
  const int dB0 = OFF_B + sA0 * 8, dB1 = OFF_B + sA1 * 8;

  // W fragment source: lane (fr,quad), wave wn -> row hcol0+(wn>>1)*16+fr,
  // half = lo (wn even) / hi (wn odd), k-cols kt + quad*8 .. +7  (16B per lane)
  const uint16_t* wptr = combW + (size_t)(hcol0 + (wn >> 1) * 16 + fr) * KC
                       + ((wn & 1) ? N_DIM : 0) + quad * 8;

  // ---- per-thread LDS read offsets (tile-invariant, u16 units) ----
  int offA[8], offB[4];
#pragma unroll
  for (int i = 0; i < 8; ++i) {
    int m = wm * 128 + i * 16 + fr;
    offA[i] = (m * 4 + (quad ^ (m & 3))) * 8;
  }
#pragma unroll
  for (int j = 0; j < 4; ++j) {
    int m = wn * 64 + j * 16 + fr;
    offB[j] = OFF_B + (m * 4 + (quad ^ (m & 3))) * 8;
  }

  f32x4 acc[8][4] = {};
  f32x4 lacc[8]   = {};

  auto STAGE = [&](uint16_t* Lp, int kt) {   // 6 global_load_lds per thread
    stage16(baseA0 + kt, Lp + dA0);
    stage16(baseA1 + kt, Lp + dA1);
    stage16(baseA0 + N_DIM + kt, Lp + OFF_A2 + dA0);
    stage16(baseA1 + N_DIM + kt, Lp + OFF_A2 + dA1);
    stage16(baseB0 + kt, Lp + dB0);
    stage16(baseB1 + kt, Lp + dB1);
  };

  // prologue: tiles 0 and 1 in flight (7 vmem each); drain tile 0 only
  short8 wf0 = *(const short8*)(wptr + 0);
  STAGE(lds, 0);
  short8 wf1 = *(const short8*)(wptr + 32);
  STAGE(lds + S_BUF, 32);
  asm volatile("s_waitcnt vmcnt(7)" ::: "memory");
  __builtin_amdgcn_s_barrier();

  int bc = 0;                            // buffer of tile t (t % 3)
  for (int t = 0; t < 14; ++t) {
    int b2 = bc + 2; if (b2 >= 3) b2 -= 3;
    short8 wf2 = *(const short8*)(wptr + (t + 2) * 32);   // W(t+2), 1 vmem
    STAGE(lds + b2 * S_BUF, (t + 2) * 32);                // tile t+2, 6 vmem
    const uint16_t* L = lds + bc * S_BUF;
    if (wn & 1) compute_tile<true >(L, offA, offB, wf0, acc, lacc);
    else        compute_tile<false>(L, offA, offB, wf0, acc, lacc);
    asm volatile("s_waitcnt vmcnt(7)" ::: "memory"); // t+1 drained, t+2 in flight
    __builtin_amdgcn_s_barrier();
    wf0 = wf1; wf1 = wf2;
    bc = (bc == 2) ? 0 : bc + 1;
  }
  { // t = 14: nothing left to stage; then drain tile 15 fully
    const uint16_t* L = lds + 2 * S_BUF;             // bc == 2
    if (wn & 1) compute_tile<true >(L, offA, offB, wf0, acc, lacc);
    else        compute_tile<false>(L, offA, offB, wf0, acc, lacc);
    asm volatile("s_waitcnt vmcnt(0)" ::: "memory");
    __builtin_amdgcn_s_barrier();
  }
  { // t = 15 (buffer 0)
    const uint16_t* L = lds;
    if (wn & 1) compute_tile<true >(L, offA, offB, wf1, acc, lacc);
    else        compute_tile<false>(L, offA, offB, wf1, acc, lacc);
  }
  __syncthreads();   // all buf0 reads done before red overwrites it

  // ---- epilogue: lin partials + FM butterfly meet in LDS, coalesced store ----
  float* red = (float*)lds;              // 256 rows x stride 36 f32 (16B-aligned rows)
  const int hgrp = (wn >> 1) * 16 + fr;
  if (!(wn & 1)) {                       // x-half partial: store
#pragma unroll
    for (int i = 0; i < 8; ++i)
#pragma unroll
      for (int r = 0; r < 4; ++r)
        red[(wm * 128 + i * 16 + quad * 4 + r) * 36 + hgrp] = lacc[i][r];
  }
  __syncthreads();
  if (wn & 1) {                          // x^2-half partial: add
#pragma unroll
    for (int i = 0; i < 8; ++i)
#pragma unroll
      for (int r = 0; r < 4; ++r)
        red[(wm * 128 + i * 16 + quad * 4 + r) * 36 + hgrp] += lacc[i][r];
  }
  __syncthreads();
  // FM: C/D col=lane&15 (hl-local), row=quad*4+r; butterfly over l bits (fr&7)
#pragma unroll
  for (int i = 0; i < 8; ++i)
#pragma unroll
    for (int j = 0; j < 4; ++j) {
      const int hin = wn * 8 + j * 2 + (fr >> 3);
#pragma unroll
      for (int r = 0; r < 4; ++r) {
        float v = acc[i][j][r];
        v = v * v;
        v += __shfl_xor(v, 1);
        v += __shfl_xor(v, 2);
        v += __shfl_xor(v, 4);
        if ((lane & 7) == 0)
          red[(wm * 128 + i * 16 + quad * 4 + r) * 36 + hin] += 0.5f * v;
      }
    }
  __syncthreads();
  {
    const int row = tid >> 1, hb = (tid & 1) * 16;
    const float* rp = red + row * 36 + hb;
    const float* bp = bias + hcol0 + hb;
    float* op = out + (size_t)(row0 + row) * H_DIM + hcol0 + hb;
#pragma unroll
    for (int i = 0; i < 4; ++i) {
      f32x4 v  = *(const f32x4*)(rp + i * 4);
      f32x4 bb = *(const f32x4*)(bp + i * 4);
      *(f32x4*)(op + i * 4) = v + bb;
    }
  }
}

extern "C" void kernel_launch(void* const* d_in, const int* in_sizes, int n_in,
                              void* d_out, int out_size, void* d_ws, size_t ws_size,
                              hipStream_t stream) {
  const float* x    = (const float*)d_in[0];  // (4096, 512)
  const float* beta = (const float*)d_in[1];  // (1024, 8, 512)
  const float* W    = (const float*)d_in[2];  // (1024, 512)
  const float* bias = (const float*)d_in[3];  // (1024,)
  float* out = (float*)d_out;                 // (4096, 1024)

  uint16_t* xcomb = (uint16_t*)d_ws;                        // 4096*1024 bf16 = 8 MB
  uint16_t* betab = xcomb + (size_t)B_DIM * KC;             // 8192*512  bf16 = 8 MB
  uint16_t* combW = betab + (size_t)HL * N_DIM;             // 1024*1024 bf16 = 2 MB

  const int prep_threads = PREP_T0 + PREP_T1 + PREP_T2;     // 851968
  prep_kernel<<<prep_threads / 256, 256, 0, stream>>>(x, beta, W, xcomb, betab, combW);

  // 512 blocks (2 rounds/CU), 256x256 tile, counted-vmcnt pipeline
  fm_kernel<<<512, 512, 0, stream>>>(xcomb, betab, combW, bias, out);
}

// Round 3
// 207.225 us; speedup vs baseline: 4.7157x; 4.7157x over previous
//
#include <hip/hip_runtime.h>
#include <stdint.h>

// Problem constants (B, N, H, L) = (4096, 512, 1024, 8)
static constexpr int B_DIM = 4096;
static constexpr int N_DIM = 512;
static constexpr int H_DIM = 1024;
static constexpr int L_DIM = 8;
static constexpr int HL    = H_DIM * L_DIM;   // 8192
static constexpr int KC    = 2 * N_DIM;       // 1024: xcomb/combW row length [lo|hi]

typedef __attribute__((ext_vector_type(8))) short short8;     // 8 bf16 (4 VGPRs)
typedef __attribute__((ext_vector_type(8))) unsigned short u16x8;
typedef __attribute__((ext_vector_type(4))) float f32x4;

// round-to-nearest-even fp32 -> bf16 (bit pattern)
__device__ __forceinline__ uint16_t f2bf(float f) {
  uint32_t u = __float_as_uint(f);
  u += 0x7fffu + ((u >> 16) & 1u);
  return (uint16_t)(u >> 16);
}

__device__ __forceinline__ void stage16(const uint16_t* g, uint16_t* l) {
  __builtin_amdgcn_global_load_lds(
      (const __attribute__((address_space(1))) void*)g,
      (__attribute__((address_space(3))) void*)l, 16, 0, 0);
}

// ---------- fused prep kernel (8 elems/thread, 16B stores) — UNCHANGED ----------
static constexpr int PREP_T0 = HL * N_DIM / 8;       // 524288
static constexpr int PREP_T1 = B_DIM * N_DIM / 8;    // 262144
static constexpr int PREP_T2 = H_DIM * N_DIM / 8;    // 65536

__global__ void prep_kernel(const float* __restrict__ x, const float* __restrict__ beta,
                            const float* __restrict__ W,
                            uint16_t* __restrict__ xcomb, uint16_t* __restrict__ betab,
                            uint16_t* __restrict__ combW) {
  int t = blockIdx.x * 256 + threadIdx.x;
  if (t < PREP_T0) {                           // beta cast
    const f32x4* src = (const f32x4*)(beta + (size_t)t * 8);
    f32x4 a = src[0], b = src[1];
    u16x8 o;
#pragma unroll
    for (int i = 0; i < 4; ++i) { o[i] = f2bf(a[i]); o[4 + i] = f2bf(b[i]); }
    *(u16x8*)(betab + (size_t)t * 8) = o;
    return;
  }
  t -= PREP_T0;
  if (t < PREP_T1) {                           // x | x^2
    int bb = t >> 6, n8 = (t & 63) * 8;
    const f32x4* src = (const f32x4*)(x + (size_t)bb * N_DIM + n8);
    f32x4 a = src[0], b = src[1];
    u16x8 lo, hi;
#pragma unroll
    for (int i = 0; i < 4; ++i) {
      lo[i] = f2bf(a[i]);        lo[4 + i] = f2bf(b[i]);
      hi[i] = f2bf(a[i] * a[i]); hi[4 + i] = f2bf(b[i] * b[i]);
    }
    *(u16x8*)(xcomb + (size_t)bb * KC + n8)         = lo;
    *(u16x8*)(xcomb + (size_t)bb * KC + N_DIM + n8) = hi;
    return;
  }
  t -= PREP_T1;                                // W | -0.5*sum_l beta^2
  int h = t >> 6, n8 = (t & 63) * 8;
  const f32x4* wsrc = (const f32x4*)(W + (size_t)h * N_DIM + n8);
  f32x4 wa = wsrc[0], wb = wsrc[1];
  u16x8 lo;
#pragma unroll
  for (int i = 0; i < 4; ++i) { lo[i] = f2bf(wa[i]); lo[4 + i] = f2bf(wb[i]); }
  *(u16x8*)(combW + (size_t)h * KC + n8) = lo;
  float s[8] = {};
#pragma unroll
  for (int l = 0; l < L_DIM; ++l) {
    const f32x4* bsrc = (const f32x4*)(beta + ((size_t)h * L_DIM + l) * N_DIM + n8);
    f32x4 a = bsrc[0], b = bsrc[1];
#pragma unroll
    for (int i = 0; i < 4; ++i) { s[i] += a[i] * a[i]; s[4 + i] += b[i] * b[i]; }
  }
  u16x8 hi;
#pragma unroll
  for (int i = 0; i < 8; ++i) hi[i] = f2bf(-0.5f * s[i]);
  *(u16x8*)(combW + (size_t)h * KC + N_DIM + n8) = hi;
}

// ---------- fused GEMM v3b: 256x256 tile, 512 threads, BK=32, triple-buffered ----------
// v3 -> v3b: FULL unroll of the i-loop in compute_tile (v3 had `#pragma unroll 4`,
// a partial unroll -> runtime i -> acc[i][j] runtime-indexed -> the whole acc array
// spilled to scratch: VGPR_Count=88, 4.5 GB scratch traffic, 940 us. Rule #20.)
//
// Counted-vmcnt pipeline (T3/T4): each iteration issues {W-regload(t+2) +
// 6 global_load_lds(t+2)} = 7 wave-uniform vmem ops, computes tile t, then waits
// vmcnt(7): drains tile t+1 while t+2 stays in flight across the raw s_barrier.
//
// Per buffer (48 KB, u16 offsets):
//   Ax  [0, 8192):      256 rows x 32 k of x      (4 chunks/row, slot = c ^ (m&3))
//   Ax2 [8192, 16384):  256 rows x 32 k of x^2
//   Bs  [16384, 24576): 256 betab rows x 32 k
// 3 buffers = 144 KB LDS, 1 block/CU, 8 waves (wm 0..1 x wn 0..3).
// W operand: per-lane 16B global loads (combW 2 MB, L2-resident), rotated through
// wf0<-wf1<-wf2 (static names, rule #20 safe).
static constexpr int S_BUF  = 24576;   // u16 per buffer (48 KB)
static constexpr int OFF_A2 = 8192;
static constexpr int OFF_B  = 16384;

template<bool ODD>
__device__ __forceinline__ void compute_tile(
    const uint16_t* __restrict__ L,
    const int (&offA)[8], const int (&offB)[4], short8 wf,
    f32x4 (&acc)[8][4], f32x4 (&lacc)[8])
{
  short8 bf[4];
#pragma unroll
  for (int j = 0; j < 4; ++j) bf[j] = *(const short8*)(L + offB[j]);
  __builtin_amdgcn_s_setprio(1);
#pragma unroll
  for (int i = 0; i < 8; ++i) {        // FULL unroll: all acc indices static
    short8 a = *(const short8*)(L + offA[i]);
    short8 a2;
    if constexpr (ODD) a2 = *(const short8*)(L + OFF_A2 + offA[i]);
    else               a2 = a;
#pragma unroll
    for (int j = 0; j < 4; ++j)
      acc[i][j] = __builtin_amdgcn_mfma_f32_16x16x32_bf16(a, bf[j], acc[i][j], 0, 0, 0);
    lacc[i] = __builtin_amdgcn_mfma_f32_16x16x32_bf16(a2, wf, lacc[i], 0, 0, 0);
  }
  __builtin_amdgcn_s_setprio(0);
}

__global__ __launch_bounds__(512) void fm_kernel(
    const uint16_t* __restrict__ xcomb,   // (B, KC)
    const uint16_t* __restrict__ betab,   // (HL, N)
    const uint16_t* __restrict__ combW,   // (H, KC)
    const float* __restrict__ bias,       // (H,)
    float* __restrict__ out)              // (B, H)
{
  __shared__ __align__(16) uint16_t lds[3 * S_BUF];   // 144 KB

  const int tid  = threadIdx.x;
  const int lane = tid & 63;
  const int wave = tid >> 6;            // 0..7
  const int wm = wave >> 2, wn = wave & 3;
  const int fr = lane & 15, quad = lane >> 4;

  // bijective XCD-chunked swizzle: 512 blocks, XCD x gets cids [64x, 64x+64)
  const int bid = blockIdx.x;
  const int cid = (bid & 7) * 64 + (bid >> 3);
  const int bx = cid >> 4, by = cid & 15;
  const int row0 = by * 256, col0 = bx * 256, hcol0 = bx * 32;

  // ---- per-thread staging sources (pre-swizzled global) + LDS dest offsets ----
  const int sA0 = tid, sA1 = tid + 512;
  const int mA0 = sA0 >> 2, cA0 = (sA0 & 3) ^ (mA0 & 3);
  const int mA1 = sA1 >> 2, cA1 = (sA1 & 3) ^ (mA1 & 3);
  const uint16_t* baseA0 = xcomb + (size_t)(row0 + mA0) * KC + cA0 * 8;
  const uint16_t* baseA1 = xcomb + (size_t)(row0 + mA1) * KC + cA1 * 8;
  const uint16_t* baseB0 = betab + (size_t)(col0 + mA0) * N_DIM + cA0 * 8;
  const uint16_t* baseB1 = betab + (size_t)(col0 + mA1) * N_DIM + cA1 * 8;
  const int dA0 = sA0 * 8, dA1 = sA1 * 8;
  const int dB0 = OFF_B + sA0 * 8, dB1 = OFF_B + sA1 * 8;

  // W fragment source: row hcol0+(wn>>1)*16+fr, half lo/hi by wn parity, cols quad*8..
  const uint16_t* wptr = combW + (size_t)(hcol0 + (wn >> 1) * 16 + fr) * KC
                       + ((wn & 1) ? N_DIM : 0) + quad * 8;

  // ---- per-thread LDS read offsets (tile-invariant, u16 units) ----
  int offA[8], offB[4];
#pragma unroll
  for (int i = 0; i < 8; ++i) {
    int m = wm * 128 + i * 16 + fr;
    offA[i] = (m * 4 + (quad ^ (m & 3))) * 8;
  }
#pragma unroll
  for (int j = 0; j < 4; ++j) {
    int m = wn * 64 + j * 16 + fr;
    offB[j] = OFF_B + (m * 4 + (quad ^ (m & 3))) * 8;
  }

  f32x4 acc[8][4] = {};
  f32x4 lacc[8]   = {};

  auto STAGE = [&](uint16_t* Lp, int kt) {   // 6 global_load_lds per thread
    stage16(baseA0 + kt, Lp + dA0);
    stage16(baseA1 + kt, Lp + dA1);
    stage16(baseA0 + N_DIM + kt, Lp + OFF_A2 + dA0);
    stage16(baseA1 + N_DIM + kt, Lp + OFF_A2 + dA1);
    stage16(baseB0 + kt, Lp + dB0);
    stage16(baseB1 + kt, Lp + dB1);
  };

  // prologue: tiles 0 and 1 in flight (7 vmem each); drain tile 0 only
  short8 wf0 = *(const short8*)(wptr + 0);
  STAGE(lds, 0);
  short8 wf1 = *(const short8*)(wptr + 32);
  STAGE(lds + S_BUF, 32);
  asm volatile("s_waitcnt vmcnt(7)" ::: "memory");
  __builtin_amdgcn_s_barrier();

  int bc = 0;                            // buffer of tile t (t % 3)
  for (int t = 0; t < 14; ++t) {
    int b2 = bc + 2; if (b2 >= 3) b2 -= 3;
    short8 wf2 = *(const short8*)(wptr + (t + 2) * 32);   // W(t+2), 1 vmem
    STAGE(lds + b2 * S_BUF, (t + 2) * 32);                // tile t+2, 6 vmem
    const uint16_t* L = lds + bc * S_BUF;
    if (wn & 1) compute_tile<true >(L, offA, offB, wf0, acc, lacc);
    else        compute_tile<false>(L, offA, offB, wf0, acc, lacc);
    asm volatile("s_waitcnt vmcnt(7)" ::: "memory"); // t+1 drained, t+2 in flight
    __builtin_amdgcn_s_barrier();
    wf0 = wf1; wf1 = wf2;
    bc = (bc == 2) ? 0 : bc + 1;
  }
  { // t = 14: nothing left to stage; then drain tile 15 fully
    const uint16_t* L = lds + 2 * S_BUF;             // bc == 2
    if (wn & 1) compute_tile<true >(L, offA, offB, wf0, acc, lacc);
    else        compute_tile<false>(L, offA, offB, wf0, acc, lacc);
    asm volatile("s_waitcnt vmcnt(0)" ::: "memory");
    __builtin_amdgcn_s_barrier();
  }
  { // t = 15 (buffer 0)
    const uint16_t* L = lds;
    if (wn & 1) compute_tile<true >(L, offA, offB, wf1, acc, lacc);
    else        compute_tile<false>(L, offA, offB, wf1, acc, lacc);
  }
  __syncthreads();   // all buf0 reads done before red overwrites it

  // ---- epilogue: lin partials + FM butterfly meet in LDS, coalesced store ----
  float* red = (float*)lds;              // 256 rows x stride 36 f32 (16B-aligned rows)
  const int hgrp = (wn >> 1) * 16 + fr;
  if (!(wn & 1)) {                       // x-half partial: store
#pragma unroll
    for (int i = 0; i < 8; ++i)
#pragma unroll
      for (int r = 0; r < 4; ++r)
        red[(wm * 128 + i * 16 + quad * 4 + r) * 36 + hgrp] = lacc[i][r];
  }
  __syncthreads();
  if (wn & 1) {                          // x^2-half partial: add
#pragma unroll
    for (int i = 0; i < 8; ++i)
#pragma unroll
      for (int r = 0; r < 4; ++r)
        red[(wm * 128 + i * 16 + quad * 4 + r) * 36 + hgrp] += lacc[i][r];
  }
  __syncthreads();
  // FM: C/D col=lane&15 (hl-local), row=quad*4+r; butterfly over l bits (fr&7)
#pragma unroll
  for (int i = 0; i < 8; ++i)
#pragma unroll
    for (int j = 0; j < 4; ++j) {
      const int hin = wn * 8 + j * 2 + (fr >> 3);
#pragma unroll
      for (int r = 0; r < 4; ++r) {
        float v = acc[i][j][r];
        v = v * v;
        v += __shfl_xor(v, 1);
        v += __shfl_xor(v, 2);
        v += __shfl_xor(v, 4);
        if ((lane & 7) == 0)
          red[(wm * 128 + i * 16 + quad * 4 + r) * 36 + hin] += 0.5f * v;
      }
    }
  __syncthreads();
  {
    const int row = tid >> 1, hb = (tid & 1) * 16;
    const float* rp = red + row * 36 + hb;
    const float* bp = bias + hcol0 + hb;
    float* op = out + (size_t)(row0 + row) * H_DIM + hcol0 + hb;
#pragma unroll
    for (int i = 0; i < 4; ++i) {
      f32x4 v  = *(const f32x4*)(rp + i * 4);
      f32x4 bb = *(const f32x4*)(bp + i * 4);
      *(f32x4*)(op + i * 4) = v + bb;
    }
  }
}

extern "C" void kernel_launch(void* const* d_in, const int* in_sizes, int n_in,
                              void* d_out, int out_size, void* d_ws, size_t ws_size,
                              hipStream_t stream) {
  const float* x    = (const float*)d_in[0];  // (4096, 512)
  const float* beta = (const float*)d_in[1];  // (1024, 8, 512)
  const float* W    = (const float*)d_in[2];  // (1024, 512)
  const float* bias = (const float*)d_in[3];  // (1024,)
  float* out = (float*)d_out;                 // (4096, 1024)

  uint16_t* xcomb = (uint16_t*)d_ws;                        // 4096*1024 bf16 = 8 MB
  uint16_t* betab = xcomb + (size_t)B_DIM * KC;             // 8192*512  bf16 = 8 MB
  uint16_t* combW = betab + (size_t)HL * N_DIM;             // 1024*1024 bf16 = 2 MB

  const int prep_threads = PREP_T0 + PREP_T1 + PREP_T2;     // 851968
  prep_kernel<<<prep_threads / 256, 256, 0, stream>>>(x, beta, W, xcomb, betab, combW);

  // 512 blocks (2 rounds/CU), 256x256 tile, counted-vmcnt pipeline
  fm_kernel<<<512, 512, 0, stream>>>(xcomb, betab, combW, bias, out);
}

// Round 4
// 205.112 us; speedup vs baseline: 4.7643x; 1.0103x over previous
//
#include <hip/hip_runtime.h>
#include <stdint.h>

// Problem constants (B, N, H, L) = (4096, 512, 1024, 8)
static constexpr int B_DIM = 4096;
static constexpr int N_DIM = 512;
static constexpr int H_DIM = 1024;
static constexpr int L_DIM = 8;
static constexpr int HL    = H_DIM * L_DIM;   // 8192
static constexpr int KC    = 2 * N_DIM;       // 1024: xcomb/combW row length [lo|hi]

typedef __attribute__((ext_vector_type(8))) short short8;     // 8 bf16 (4 VGPRs)
typedef __attribute__((ext_vector_type(8))) unsigned short u16x8;
typedef __attribute__((ext_vector_type(4))) float f32x4;

// round-to-nearest-even fp32 -> bf16 (bit pattern)
__device__ __forceinline__ uint16_t f2bf(float f) {
  uint32_t u = __float_as_uint(f);
  u += 0x7fffu + ((u >> 16) & 1u);
  return (uint16_t)(u >> 16);
}

__device__ __forceinline__ void stage16(const uint16_t* g, uint16_t* l) {
  __builtin_amdgcn_global_load_lds(
      (const __attribute__((address_space(1))) void*)g,
      (__attribute__((address_space(3))) void*)l, 16, 0, 0);
}

// ---------- fused prep kernel (8 elems/thread, 16B stores) — UNCHANGED ----------
static constexpr int PREP_T0 = HL * N_DIM / 8;       // 524288
static constexpr int PREP_T1 = B_DIM * N_DIM / 8;    // 262144
static constexpr int PREP_T2 = H_DIM * N_DIM / 8;    // 65536

__global__ void prep_kernel(const float* __restrict__ x, const float* __restrict__ beta,
                            const float* __restrict__ W,
                            uint16_t* __restrict__ xcomb, uint16_t* __restrict__ betab,
                            uint16_t* __restrict__ combW) {
  int t = blockIdx.x * 256 + threadIdx.x;
  if (t < PREP_T0) {                           // beta cast
    const f32x4* src = (const f32x4*)(beta + (size_t)t * 8);
    f32x4 a = src[0], b = src[1];
    u16x8 o;
#pragma unroll
    for (int i = 0; i < 4; ++i) { o[i] = f2bf(a[i]); o[4 + i] = f2bf(b[i]); }
    *(u16x8*)(betab + (size_t)t * 8) = o;
    return;
  }
  t -= PREP_T0;
  if (t < PREP_T1) {                           // x | x^2
    int bb = t >> 6, n8 = (t & 63) * 8;
    const f32x4* src = (const f32x4*)(x + (size_t)bb * N_DIM + n8);
    f32x4 a = src[0], b = src[1];
    u16x8 lo, hi;
#pragma unroll
    for (int i = 0; i < 4; ++i) {
      lo[i] = f2bf(a[i]);        lo[4 + i] = f2bf(b[i]);
      hi[i] = f2bf(a[i] * a[i]); hi[4 + i] = f2bf(b[i] * b[i]);
    }
    *(u16x8*)(xcomb + (size_t)bb * KC + n8)         = lo;
    *(u16x8*)(xcomb + (size_t)bb * KC + N_DIM + n8) = hi;
    return;
  }
  t -= PREP_T1;                                // W | -0.5*sum_l beta^2
  int h = t >> 6, n8 = (t & 63) * 8;
  const f32x4* wsrc = (const f32x4*)(W + (size_t)h * N_DIM + n8);
  f32x4 wa = wsrc[0], wb = wsrc[1];
  u16x8 lo;
#pragma unroll
  for (int i = 0; i < 4; ++i) { lo[i] = f2bf(wa[i]); lo[4 + i] = f2bf(wb[i]); }
  *(u16x8*)(combW + (size_t)h * KC + n8) = lo;
  float s[8] = {};
#pragma unroll
  for (int l = 0; l < L_DIM; ++l) {
    const f32x4* bsrc = (const f32x4*)(beta + ((size_t)h * L_DIM + l) * N_DIM + n8);
    f32x4 a = bsrc[0], b = bsrc[1];
#pragma unroll
    for (int i = 0; i < 4; ++i) { s[i] += a[i] * a[i]; s[4 + i] += b[i] * b[i]; }
  }
  u16x8 hi;
#pragma unroll
  for (int i = 0; i < 8; ++i) hi[i] = f2bf(-0.5f * s[i]);
  *(u16x8*)(combW + (size_t)h * KC + N_DIM + n8) = hi;
}

// ---------- fused GEMM v4: 256x256 tile, 512 threads, BK=32, triple-buffered ----------
// v3b -> v4: __launch_bounds__(512, 2). v3b's bare __launch_bounds__(512) let the
// allocator target 4 waves/SIMD (128-VGPR cap) even though 144 KB LDS pins us to
// 1 block/CU (2 waves/SIMD). Result: VGPR_Count=128, ~100 MB scratch each way
// (FETCH 120 MB / WRITE 117 MB vs ~40/16 expected), MfmaUtil 12.6%. Declaring
// 2 waves/EU raises the cap to 256 (live state ~230) -> no spill.
//
// Counted-vmcnt pipeline (T3/T4): each iteration issues {W-regload(t+2) +
// 6 global_load_lds(t+2)} = 7 wave-uniform vmem ops, computes tile t, then waits
// vmcnt(7): drains tile t+1 while t+2 stays in flight across the raw s_barrier.
//
// Per buffer (48 KB, u16 offsets):
//   Ax  [0, 8192):      256 rows x 32 k of x      (4 chunks/row, slot = c ^ (m&3))
//   Ax2 [8192, 16384):  256 rows x 32 k of x^2
//   Bs  [16384, 24576): 256 betab rows x 32 k
// 3 buffers = 144 KB LDS, 1 block/CU, 8 waves (wm 0..1 x wn 0..3).
// W operand: per-lane 16B global loads (combW 2 MB, L2-resident), rotated through
// wf0<-wf1<-wf2 (static names, rule #20 safe).
static constexpr int S_BUF  = 24576;   // u16 per buffer (48 KB)
static constexpr int OFF_A2 = 8192;
static constexpr int OFF_B  = 16384;

template<bool ODD>
__device__ __forceinline__ void compute_tile(
    const uint16_t* __restrict__ L,
    const int (&offA)[8], const int (&offB)[4], short8 wf,
    f32x4 (&acc)[8][4], f32x4 (&lacc)[8])
{
  short8 bf[4];
#pragma unroll
  for (int j = 0; j < 4; ++j) bf[j] = *(const short8*)(L + offB[j]);
  __builtin_amdgcn_s_setprio(1);
#pragma unroll
  for (int i = 0; i < 8; ++i) {        // FULL unroll: all acc indices static
    short8 a = *(const short8*)(L + offA[i]);
    short8 a2;
    if constexpr (ODD) a2 = *(const short8*)(L + OFF_A2 + offA[i]);
    else               a2 = a;
#pragma unroll
    for (int j = 0; j < 4; ++j)
      acc[i][j] = __builtin_amdgcn_mfma_f32_16x16x32_bf16(a, bf[j], acc[i][j], 0, 0, 0);
    lacc[i] = __builtin_amdgcn_mfma_f32_16x16x32_bf16(a2, wf, lacc[i], 0, 0, 0);
  }
  __builtin_amdgcn_s_setprio(0);
}

__global__ __launch_bounds__(512, 2) void fm_kernel(
    const uint16_t* __restrict__ xcomb,   // (B, KC)
    const uint16_t* __restrict__ betab,   // (HL, N)
    const uint16_t* __restrict__ combW,   // (H, KC)
    const float* __restrict__ bias,       // (H,)
    float* __restrict__ out)              // (B, H)
{
  __shared__ __align__(16) uint16_t lds[3 * S_BUF];   // 144 KB

  const int tid  = threadIdx.x;
  const int lane = tid & 63;
  const int wave = tid >> 6;            // 0..7
  const int wm = wave >> 2, wn = wave & 3;
  const int fr = lane & 15, quad = lane >> 4;

  // bijective XCD-chunked swizzle: 512 blocks, XCD x gets cids [64x, 64x+64)
  const int bid = blockIdx.x;
  const int cid = (bid & 7) * 64 + (bid >> 3);
  const int bx = cid >> 4, by = cid & 15;
  const int row0 = by * 256, col0 = bx * 256, hcol0 = bx * 32;

  // ---- per-thread staging sources (pre-swizzled global) + LDS dest offsets ----
  const int sA0 = tid, sA1 = tid + 512;
  const int mA0 = sA0 >> 2, cA0 = (sA0 & 3) ^ (mA0 & 3);
  const int mA1 = sA1 >> 2, cA1 = (sA1 & 3) ^ (mA1 & 3);
  const uint16_t* baseA0 = xcomb + (size_t)(row0 + mA0) * KC + cA0 * 8;
  const uint16_t* baseA1 = xcomb + (size_t)(row0 + mA1) * KC + cA1 * 8;
  const uint16_t* baseB0 = betab + (size_t)(col0 + mA0) * N_DIM + cA0 * 8;
  const uint16_t* baseB1 = betab + (size_t)(col0 + mA1) * N_DIM + cA1 * 8;
  const int dA0 = sA0 * 8, dA1 = sA1 * 8;
  const int dB0 = OFF_B + sA0 * 8, dB1 = OFF_B + sA1 * 8;

  // W fragment source: row hcol0+(wn>>1)*16+fr, half lo/hi by wn parity, cols quad*8..
  const uint16_t* wptr = combW + (size_t)(hcol0 + (wn >> 1) * 16 + fr) * KC
                       + ((wn & 1) ? N_DIM : 0) + quad * 8;

  // ---- per-thread LDS read offsets (tile-invariant, u16 units) ----
  int offA[8], offB[4];
#pragma unroll
  for (int i = 0; i < 8; ++i) {
    int m = wm * 128 + i * 16 + fr;
    offA[i] = (m * 4 + (quad ^ (m & 3))) * 8;
  }
#pragma unroll
  for (int j = 0; j < 4; ++j) {
    int m = wn * 64 + j * 16 + fr;
    offB[j] = OFF_B + (m * 4 + (quad ^ (m & 3))) * 8;
  }

  f32x4 acc[8][4] = {};
  f32x4 lacc[8]   = {};

  auto STAGE = [&](uint16_t* Lp, int kt) {   // 6 global_load_lds per thread
    stage16(baseA0 + kt, Lp + dA0);
    stage16(baseA1 + kt, Lp + dA1);
    stage16(baseA0 + N_DIM + kt, Lp + OFF_A2 + dA0);
    stage16(baseA1 + N_DIM + kt, Lp + OFF_A2 + dA1);
    stage16(baseB0 + kt, Lp + dB0);
    stage16(baseB1 + kt, Lp + dB1);
  };

  // prologue: tiles 0 and 1 in flight (7 vmem each); drain tile 0 only
  short8 wf0 = *(const short8*)(wptr + 0);
  STAGE(lds, 0);
  short8 wf1 = *(const short8*)(wptr + 32);
  STAGE(lds + S_BUF, 32);
  asm volatile("s_waitcnt vmcnt(7)" ::: "memory");
  __builtin_amdgcn_s_barrier();

  int bc = 0;                            // buffer of tile t (t % 3)
  for (int t = 0; t < 14; ++t) {
    int b2 = bc + 2; if (b2 >= 3) b2 -= 3;
    short8 wf2 = *(const short8*)(wptr + (t + 2) * 32);   // W(t+2), 1 vmem
    STAGE(lds + b2 * S_BUF, (t + 2) * 32);                // tile t+2, 6 vmem
    const uint16_t* L = lds + bc * S_BUF;
    if (wn & 1) compute_tile<true >(L, offA, offB, wf0, acc, lacc);
    else        compute_tile<false>(L, offA, offB, wf0, acc, lacc);
    asm volatile("s_waitcnt vmcnt(7)" ::: "memory"); // t+1 drained, t+2 in flight
    __builtin_amdgcn_s_barrier();
    wf0 = wf1; wf1 = wf2;
    bc = (bc == 2) ? 0 : bc + 1;
  }
  { // t = 14: nothing left to stage; then drain tile 15 fully
    const uint16_t* L = lds + 2 * S_BUF;             // bc == 2
    if (wn & 1) compute_tile<true >(L, offA, offB, wf0, acc, lacc);
    else        compute_tile<false>(L, offA, offB, wf0, acc, lacc);
    asm volatile("s_waitcnt vmcnt(0)" ::: "memory");
    __builtin_amdgcn_s_barrier();
  }
  { // t = 15 (buffer 0)
    const uint16_t* L = lds;
    if (wn & 1) compute_tile<true >(L, offA, offB, wf1, acc, lacc);
    else        compute_tile<false>(L, offA, offB, wf1, acc, lacc);
  }
  __syncthreads();   // all buf0 reads done before red overwrites it

  // ---- epilogue: lin partials + FM butterfly meet in LDS, coalesced store ----
  float* red = (float*)lds;              // 256 rows x stride 36 f32 (16B-aligned rows)
  const int hgrp = (wn >> 1) * 16 + fr;
  if (!(wn & 1)) {                       // x-half partial: store
#pragma unroll
    for (int i = 0; i < 8; ++i)
#pragma unroll
      for (int r = 0; r < 4; ++r)
        red[(wm * 128 + i * 16 + quad * 4 + r) * 36 + hgrp] = lacc[i][r];
  }
  __syncthreads();
  if (wn & 1) {                          // x^2-half partial: add
#pragma unroll
    for (int i = 0; i < 8; ++i)
#pragma unroll
      for (int r = 0; r < 4; ++r)
        red[(wm * 128 + i * 16 + quad * 4 + r) * 36 + hgrp] += lacc[i][r];
  }
  __syncthreads();
  // FM: C/D col=lane&15 (hl-local), row=quad*4+r; butterfly over l bits (fr&7)
#pragma unroll
  for (int i = 0; i < 8; ++i)
#pragma unroll
    for (int j = 0; j < 4; ++j) {
      const int hin = wn * 8 + j * 2 + (fr >> 3);
#pragma unroll
      for (int r = 0; r < 4; ++r) {
        float v = acc[i][j][r];
        v = v * v;
        v += __shfl_xor(v, 1);
        v += __shfl_xor(v, 2);
        v += __shfl_xor(v, 4);
        if ((lane & 7) == 0)
          red[(wm * 128 + i * 16 + quad * 4 + r) * 36 + hin] += 0.5f * v;
      }
    }
  __syncthreads();
  {
    const int row = tid >> 1, hb = (tid & 1) * 16;
    const float* rp = red + row * 36 + hb;
    const float* bp = bias + hcol0 + hb;
    float* op = out + (size_t)(row0 + row) * H_DIM + hcol0 + hb;
#pragma unroll
    for (int i = 0; i < 4; ++i) {
      f32x4 v  = *(const f32x4*)(rp + i * 4);
      f32x4 bb = *(const f32x4*)(bp + i * 4);
      *(f32x4*)(op + i * 4) = v + bb;
    }
  }
}

extern "C" void kernel_launch(void* const* d_in, const int* in_sizes, int n_in,
                              void* d_out, int out_size, void* d_ws, size_t ws_size,
                              hipStream_t stream) {
  const float* x    = (const float*)d_in[0];  // (4096, 512)
  const float* beta = (const float*)d_in[1];  // (1024, 8, 512)
  const float* W    = (const float*)d_in[2];  // (1024, 512)
  const float* bias = (const float*)d_in[3];  // (1024,)
  float* out = (float*)d_out;                 // (4096, 1024)

  uint16_t* xcomb = (uint16_t*)d_ws;                        // 4096*1024 bf16 = 8 MB
  uint16_t* betab = xcomb + (size_t)B_DIM * KC;             // 8192*512  bf16 = 8 MB
  uint16_t* combW = betab + (size_t)HL * N_DIM;             // 1024*1024 bf16 = 2 MB

  const int prep_threads = PREP_T0 + PREP_T1 + PREP_T2;     // 851968
  prep_kernel<<<prep_threads / 256, 256, 0, stream>>>(x, beta, W, xcomb, betab, combW);

  // 512 blocks (2 rounds/CU), 256x256 tile, counted-vmcnt pipeline
  fm_kernel<<<512, 512, 0, stream>>>(xcomb, betab, combW, bias, out);
}

// Round 5
// 204.817 us; speedup vs baseline: 4.7711x; 1.0014x over previous
//
#include <hip/hip_runtime.h>
#include <stdint.h>

// Problem constants (B, N, H, L) = (4096, 512, 1024, 8)
static constexpr int B_DIM = 4096;
static constexpr int N_DIM = 512;
static constexpr int H_DIM = 1024;
static constexpr int L_DIM = 8;
static constexpr int HL    = H_DIM * L_DIM;   // 8192
static constexpr int KC    = 2 * N_DIM;       // 1024: xcomb/combW row length [lo|hi]

typedef __attribute__((ext_vector_type(8))) short short8;     // 8 bf16 (4 VGPRs)
typedef __attribute__((ext_vector_type(8))) unsigned short u16x8;
typedef __attribute__((ext_vector_type(4))) float f32x4;

// round-to-nearest-even fp32 -> bf16 (bit pattern)
__device__ __forceinline__ uint16_t f2bf(float f) {
  uint32_t u = __float_as_uint(f);
  u += 0x7fffu + ((u >> 16) & 1u);
  return (uint16_t)(u >> 16);
}

__device__ __forceinline__ void stage16(const uint16_t* g, uint16_t* l) {
  __builtin_amdgcn_global_load_lds(
      (const __attribute__((address_space(1))) void*)g,
      (__attribute__((address_space(3))) void*)l, 16, 0, 0);
}

// ---------- fused prep kernel (8 elems/thread, 16B stores) — UNCHANGED ----------
static constexpr int PREP_T0 = HL * N_DIM / 8;       // 524288
static constexpr int PREP_T1 = B_DIM * N_DIM / 8;    // 262144
static constexpr int PREP_T2 = H_DIM * N_DIM / 8;    // 65536

__global__ void prep_kernel(const float* __restrict__ x, const float* __restrict__ beta,
                            const float* __restrict__ W,
                            uint16_t* __restrict__ xcomb, uint16_t* __restrict__ betab,
                            uint16_t* __restrict__ combW) {
  int t = blockIdx.x * 256 + threadIdx.x;
  if (t < PREP_T0) {                           // beta cast
    const f32x4* src = (const f32x4*)(beta + (size_t)t * 8);
    f32x4 a = src[0], b = src[1];
    u16x8 o;
#pragma unroll
    for (int i = 0; i < 4; ++i) { o[i] = f2bf(a[i]); o[4 + i] = f2bf(b[i]); }
    *(u16x8*)(betab + (size_t)t * 8) = o;
    return;
  }
  t -= PREP_T0;
  if (t < PREP_T1) {                           // x | x^2
    int bb = t >> 6, n8 = (t & 63) * 8;
    const f32x4* src = (const f32x4*)(x + (size_t)bb * N_DIM + n8);
    f32x4 a = src[0], b = src[1];
    u16x8 lo, hi;
#pragma unroll
    for (int i = 0; i < 4; ++i) {
      lo[i] = f2bf(a[i]);        lo[4 + i] = f2bf(b[i]);
      hi[i] = f2bf(a[i] * a[i]); hi[4 + i] = f2bf(b[i] * b[i]);
    }
    *(u16x8*)(xcomb + (size_t)bb * KC + n8)         = lo;
    *(u16x8*)(xcomb + (size_t)bb * KC + N_DIM + n8) = hi;
    return;
  }
  t -= PREP_T1;                                // W | -0.5*sum_l beta^2
  int h = t >> 6, n8 = (t & 63) * 8;
  const f32x4* wsrc = (const f32x4*)(W + (size_t)h * N_DIM + n8);
  f32x4 wa = wsrc[0], wb = wsrc[1];
  u16x8 lo;
#pragma unroll
  for (int i = 0; i < 4; ++i) { lo[i] = f2bf(wa[i]); lo[4 + i] = f2bf(wb[i]); }
  *(u16x8*)(combW + (size_t)h * KC + n8) = lo;
  float s[8] = {};
#pragma unroll
  for (int l = 0; l < L_DIM; ++l) {
    const f32x4* bsrc = (const f32x4*)(beta + ((size_t)h * L_DIM + l) * N_DIM + n8);
    f32x4 a = bsrc[0], b = bsrc[1];
#pragma unroll
    for (int i = 0; i < 4; ++i) { s[i] += a[i] * a[i]; s[4 + i] += b[i] * b[i]; }
  }
  u16x8 hi;
#pragma unroll
  for (int i = 0; i < 8; ++i) hi[i] = f2bf(-0.5f * s[i]);
  *(u16x8*)(combW + (size_t)h * KC + N_DIM + n8) = hi;
}

// ---------- fused GEMM v5: 256x256 tile, 512 threads, BK=32, triple-buffered ----------
// v4 -> v5: force the VGPR budget with amdgpu_waves_per_eu(2,2). v4's
// __launch_bounds__(512,2) produced a bit-identical binary (VGPR_Count=128,
// ~98 MB scratch each way, MfmaUtil 12.6%): the allocator targets 4 waves/SIMD
// (128-VGPR cap) because its occupancy model ignores the 144 KB LDS that already
// pins us to 1 block/CU = 2 waves/SIMD. min=max=2 waves/EU sets the register
// budget to 512/2 = 256 (live state ~230) -> no spill, and costs zero occupancy.
//
// Counted-vmcnt pipeline (T3/T4): each iteration issues {W-regload(t+2) +
// 6 global_load_lds(t+2)} = 7 wave-uniform vmem ops, computes tile t, then waits
// vmcnt(7): drains tile t+1 while t+2 stays in flight across the raw s_barrier.
//
// Per buffer (48 KB, u16 offsets):
//   Ax  [0, 8192):      256 rows x 32 k of x      (4 chunks/row, slot = c ^ (m&3))
//   Ax2 [8192, 16384):  256 rows x 32 k of x^2
//   Bs  [16384, 24576): 256 betab rows x 32 k
// 3 buffers = 144 KB LDS, 1 block/CU, 8 waves (wm 0..1 x wn 0..3).
// W operand: per-lane 16B global loads (combW 2 MB, L2-resident), rotated through
// wf0<-wf1<-wf2 (static names, rule #20 safe).
static constexpr int S_BUF  = 24576;   // u16 per buffer (48 KB)
static constexpr int OFF_A2 = 8192;
static constexpr int OFF_B  = 16384;

template<bool ODD>
__device__ __forceinline__ void compute_tile(
    const uint16_t* __restrict__ L,
    const int (&offA)[8], const int (&offB)[4], short8 wf,
    f32x4 (&acc)[8][4], f32x4 (&lacc)[8])
{
  short8 bf[4];
#pragma unroll
  for (int j = 0; j < 4; ++j) bf[j] = *(const short8*)(L + offB[j]);
  __builtin_amdgcn_s_setprio(1);
#pragma unroll
  for (int i = 0; i < 8; ++i) {        // FULL unroll: all acc indices static
    short8 a = *(const short8*)(L + offA[i]);
    short8 a2;
    if constexpr (ODD) a2 = *(const short8*)(L + OFF_A2 + offA[i]);
    else               a2 = a;
#pragma unroll
    for (int j = 0; j < 4; ++j)
      acc[i][j] = __builtin_amdgcn_mfma_f32_16x16x32_bf16(a, bf[j], acc[i][j], 0, 0, 0);
    lacc[i] = __builtin_amdgcn_mfma_f32_16x16x32_bf16(a2, wf, lacc[i], 0, 0, 0);
  }
  __builtin_amdgcn_s_setprio(0);
}

__global__ __launch_bounds__(512)
__attribute__((amdgpu_waves_per_eu(2, 2)))
void fm_kernel(
    const uint16_t* __restrict__ xcomb,   // (B, KC)
    const uint16_t* __restrict__ betab,   // (HL, N)
    const uint16_t* __restrict__ combW,   // (H, KC)
    const float* __restrict__ bias,       // (H,)
    float* __restrict__ out)              // (B, H)
{
  __shared__ __align__(16) uint16_t lds[3 * S_BUF];   // 144 KB

  const int tid  = threadIdx.x;
  const int lane = tid & 63;
  const int wave = tid >> 6;            // 0..7
  const int wm = wave >> 2, wn = wave & 3;
  const int fr = lane & 15, quad = lane >> 4;

  // bijective XCD-chunked swizzle: 512 blocks, XCD x gets cids [64x, 64x+64)
  const int bid = blockIdx.x;
  const int cid = (bid & 7) * 64 + (bid >> 3);
  const int bx = cid >> 4, by = cid & 15;
  const int row0 = by * 256, col0 = bx * 256, hcol0 = bx * 32;

  // ---- per-thread staging sources (pre-swizzled global) + LDS dest offsets ----
  const int sA0 = tid, sA1 = tid + 512;
  const int mA0 = sA0 >> 2, cA0 = (sA0 & 3) ^ (mA0 & 3);
  const int mA1 = sA1 >> 2, cA1 = (sA1 & 3) ^ (mA1 & 3);
  const uint16_t* baseA0 = xcomb + (size_t)(row0 + mA0) * KC + cA0 * 8;
  const uint16_t* baseA1 = xcomb + (size_t)(row0 + mA1) * KC + cA1 * 8;
  const uint16_t* baseB0 = betab + (size_t)(col0 + mA0) * N_DIM + cA0 * 8;
  const uint16_t* baseB1 = betab + (size_t)(col0 + mA1) * N_DIM + cA1 * 8;
  const int dA0 = sA0 * 8, dA1 = sA1 * 8;
  const int dB0 = OFF_B + sA0 * 8, dB1 = OFF_B + sA1 * 8;

  // W fragment source: row hcol0+(wn>>1)*16+fr, half lo/hi by wn parity, cols quad*8..
  const uint16_t* wptr = combW + (size_t)(hcol0 + (wn >> 1) * 16 + fr) * KC
                       + ((wn & 1) ? N_DIM : 0) + quad * 8;

  // ---- per-thread LDS read offsets (tile-invariant, u16 units) ----
  int offA[8], offB[4];
#pragma unroll
  for (int i = 0; i < 8; ++i) {
    int m = wm * 128 + i * 16 + fr;
    offA[i] = (m * 4 + (quad ^ (m & 3))) * 8;
  }
#pragma unroll
  for (int j = 0; j < 4; ++j) {
    int m = wn * 64 + j * 16 + fr;
    offB[j] = OFF_B + (m * 4 + (quad ^ (m & 3))) * 8;
  }

  f32x4 acc[8][4] = {};
  f32x4 lacc[8]   = {};

  auto STAGE = [&](uint16_t* Lp, int kt) {   // 6 global_load_lds per thread
    stage16(baseA0 + kt, Lp + dA0);
    stage16(baseA1 + kt, Lp + dA1);
    stage16(baseA0 + N_DIM + kt, Lp + OFF_A2 + dA0);
    stage16(baseA1 + N_DIM + kt, Lp + OFF_A2 + dA1);
    stage16(baseB0 + kt, Lp + dB0);
    stage16(baseB1 + kt, Lp + dB1);
  };

  // prologue: tiles 0 and 1 in flight (7 vmem each); drain tile 0 only
  short8 wf0 = *(const short8*)(wptr + 0);
  STAGE(lds, 0);
  short8 wf1 = *(const short8*)(wptr + 32);
  STAGE(lds + S_BUF, 32);
  asm volatile("s_waitcnt vmcnt(7)" ::: "memory");
  __builtin_amdgcn_s_barrier();

  int bc = 0;                            // buffer of tile t (t % 3)
  for (int t = 0; t < 14; ++t) {
    int b2 = bc + 2; if (b2 >= 3) b2 -= 3;
    short8 wf2 = *(const short8*)(wptr + (t + 2) * 32);   // W(t+2), 1 vmem
    STAGE(lds + b2 * S_BUF, (t + 2) * 32);                // tile t+2, 6 vmem
    const uint16_t* L = lds + bc * S_BUF;
    if (wn & 1) compute_tile<true >(L, offA, offB, wf0, acc, lacc);
    else        compute_tile<false>(L, offA, offB, wf0, acc, lacc);
    asm volatile("s_waitcnt vmcnt(7)" ::: "memory"); // t+1 drained, t+2 in flight
    __builtin_amdgcn_s_barrier();
    wf0 = wf1; wf1 = wf2;
    bc = (bc == 2) ? 0 : bc + 1;
  }
  { // t = 14: nothing left to stage; then drain tile 15 fully
    const uint16_t* L = lds + 2 * S_BUF;             // bc == 2
    if (wn & 1) compute_tile<true >(L, offA, offB, wf0, acc, lacc);
    else        compute_tile<false>(L, offA, offB, wf0, acc, lacc);
    asm volatile("s_waitcnt vmcnt(0)" ::: "memory");
    __builtin_amdgcn_s_barrier();
  }
  { // t = 15 (buffer 0)
    const uint16_t* L = lds;
    if (wn & 1) compute_tile<true >(L, offA, offB, wf1, acc, lacc);
    else        compute_tile<false>(L, offA, offB, wf1, acc, lacc);
  }
  __syncthreads();   // all buf0 reads done before red overwrites it

  // ---- epilogue: lin partials + FM butterfly meet in LDS, coalesced store ----
  float* red = (float*)lds;              // 256 rows x stride 36 f32 (16B-aligned rows)
  const int hgrp = (wn >> 1) * 16 + fr;
  if (!(wn & 1)) {                       // x-half partial: store
#pragma unroll
    for (int i = 0; i < 8; ++i)
#pragma unroll
      for (int r = 0; r < 4; ++r)
        red[(wm * 128 + i * 16 + quad * 4 + r) * 36 + hgrp] = lacc[i][r];
  }
  __syncthreads();
  if (wn & 1) {                          // x^2-half partial: add
#pragma unroll
    for (int i = 0; i < 8; ++i)
#pragma unroll
      for (int r = 0; r < 4; ++r)
        red[(wm * 128 + i * 16 + quad * 4 + r) * 36 + hgrp] += lacc[i][r];
  }
  __syncthreads();
  // FM: C/D col=lane&15 (hl-local), row=quad*4+r; butterfly over l bits (fr&7)
#pragma unroll
  for (int i = 0; i < 8; ++i)
#pragma unroll
    for (int j = 0; j < 4; ++j) {
      const int hin = wn * 8 + j * 2 + (fr >> 3);
#pragma unroll
      for (int r = 0; r < 4; ++r) {
        float v = acc[i][j][r];
        v = v * v;
        v += __shfl_xor(v, 1);
        v += __shfl_xor(v, 2);
        v += __shfl_xor(v, 4);
        if ((lane & 7) == 0)
          red[(wm * 128 + i * 16 + quad * 4 + r) * 36 + hin] += 0.5f * v;
      }
    }
  __syncthreads();
  {
    const int row = tid >> 1, hb = (tid & 1) * 16;
    const float* rp = red + row * 36 + hb;
    const float* bp = bias + hcol0 + hb;
    float* op = out + (size_t)(row0 + row) * H_DIM + hcol0 + hb;
#pragma unroll
    for (int i = 0; i < 4; ++i) {
      f32x4 v  = *(const f32x4*)(rp + i * 4);
      f32x4 bb = *(const f32x4*)(bp + i * 4);
      *(f32x4*)(op + i * 4) = v + bb;
    }
  }
}

extern "C" void kernel_launch(void* const* d_in, const int* in_sizes, int n_in,
                              void* d_out, int out_size, void* d_ws, size_t ws_size,
                              hipStream_t stream) {
  const float* x    = (const float*)d_in[0];  // (4096, 512)
  const float* beta = (const float*)d_in[1];  // (1024, 8, 512)
  const float* W    = (const float*)d_in[2];  // (1024, 512)
  const float* bias = (const float*)d_in[3];  // (1024,)
  float* out = (float*)d_out;                 // (4096, 1024)

  uint16_t* xcomb = (uint16_t*)d_ws;                        // 4096*1024 bf16 = 8 MB
  uint16_t* betab = xcomb + (size_t)B_DIM * KC;             // 8192*512  bf16 = 8 MB
  uint16_t* combW = betab + (size_t)HL * N_DIM;             // 1024*1024 bf16 = 2 MB

  const int prep_threads = PREP_T0 + PREP_T1 + PREP_T2;     // 851968
  prep_kernel<<<prep_threads / 256, 256, 0, stream>>>(x, beta, W, xcomb, betab, combW);

  // 512 blocks (2 rounds/CU), 256x256 tile, counted-vmcnt pipeline
  fm_kernel<<<512, 512, 0, stream>>>(xcomb, betab, combW, bias, out);
}